// Round 4
// baseline (149.467 us; speedup 1.0000x reference)
//
#include <hip/hip_runtime.h>

typedef __bf16 bf16x8 __attribute__((ext_vector_type(8)));
typedef __bf16 bf16x4 __attribute__((ext_vector_type(4)));
typedef __bf16 bf16x2 __attribute__((ext_vector_type(2)));
typedef float  f32x4  __attribute__((ext_vector_type(4)));

#define NPIX  3136      // 56*56 = 49*64 = 98*32 (no tails)
#define WIMG  56
#define CCH   128
#define NH    4
#define HD    32
// 32^-0.5 * log2(e): q pre-scaled so softmax uses exp2 directly
#define QSCALE 0.2550565470841439f

#if __has_builtin(__builtin_amdgcn_exp2f)
#define FEXP2(x) __builtin_amdgcn_exp2f(x)
#else
#define FEXP2(x) __expf((x) * 0.6931471805599453f)
#endif

// MFMA 16x16x32 fragment maps (HW-verified R1-R3):
//   A[m=lane&15][k=(lane>>4)*8+j]   B[k=(lane>>4)*8+j][n=lane&15]
//   D: col(n)=lane&15, row(m)=(lane>>4)*4+reg
// Key permutation inside each 64-key block: storage s holds key 16*(s&3)+(s>>2)
// so QK chunk-c output packs to s=4*col+c (one b64 LDS write/lane), and vP is
// pre-permuted to match (summation-index permutation = free).

// ---------------------------------------------------------------------------
// K1: qkv = qkv_w @ x + qkv_b, bf16 MFMA (M=384, K=128, N=6272).
// grid (49, 6, 2), block 256. x staged in LDS as [px][c] (+8 pad) so B-frags
// are single ds_read_b128 (2-way bank phase = free) -- R3 used [c][px] which
// cost 128 ds_read_u16 per wave.
// ---------------------------------------------------------------------------
__global__ __launch_bounds__(256) void k_qkv(
    const float* __restrict__ x, const float* __restrict__ qkv_w,
    const float* __restrict__ qkv_b,
    __bf16* __restrict__ qT, __bf16* __restrict__ kT,
    __bf16* __restrict__ vT, __bf16* __restrict__ vP)
{
    __shared__ __bf16 xl[64][136];                 // 17.4 KB, row stride 272B
    const int tid = threadIdx.x;
    const int w = tid >> 6, lane = tid & 63;
    const int col = lane & 15, g = lane >> 4;
    const int px0 = blockIdx.x * 64;
    const int oslab = blockIdx.y;                  // 0-1 q, 2-3 k, 4-5 v
    const int b = blockIdx.z;
    const int obase = oslab * 64 + w * 16;

    {   // stage: thread = (px, 4 channels) x 8 passes; coalesced dword loads,
        // packed b64 LDS writes (8-way phase on writes, tiny fraction of time)
        const int px = tid & 63, cq = tid >> 6;
        const float* xp = x + (size_t)b * CCH * NPIX + px0 + px;
        #pragma unroll
        for (int i = 0; i < 8; ++i) {
            const int c0 = cq * 4 + i * 16;
            const float v0 = xp[(size_t)(c0 + 0) * NPIX];
            const float v1 = xp[(size_t)(c0 + 1) * NPIX];
            const float v2 = xp[(size_t)(c0 + 2) * NPIX];
            const float v3 = xp[(size_t)(c0 + 3) * NPIX];
            bf16x4 bv = {(__bf16)v0, (__bf16)v1, (__bf16)v2, (__bf16)v3};
            *(bf16x4*)&xl[px][c0] = bv;
        }
    }
    __syncthreads();

    f32x4 acc[4];
    #pragma unroll
    for (int a = 0; a < 4; ++a) acc[a] = (f32x4){0.f, 0.f, 0.f, 0.f};

    const float* wrow = qkv_w + (size_t)(obase + col) * CCH;
    #pragma unroll
    for (int ks = 0; ks < 4; ++ks) {
        const int c0 = ks * 32 + g * 8;
        const float4 wA = *(const float4*)(wrow + c0);
        const float4 wB = *(const float4*)(wrow + c0 + 4);
        bf16x8 af = {(__bf16)wA.x, (__bf16)wA.y, (__bf16)wA.z, (__bf16)wA.w,
                     (__bf16)wB.x, (__bf16)wB.y, (__bf16)wB.z, (__bf16)wB.w};
        #pragma unroll
        for (int a = 0; a < 4; ++a) {
            const bf16x8 bf_ = *(const bf16x8*)&xl[16 * a + col][c0];  // one b128
            acc[a] = __builtin_amdgcn_mfma_f32_16x16x32_bf16(af, bf_, acc[a], 0, 0, 0);
        }
    }

    const int orow = obase + g * 4;
    const f32x4 bias4 = *(const f32x4*)(qkv_b + orow);

    if (oslab < 2) {                               // ---- q (scaled) ----
        const int h = orow >> 5, d0 = orow & 31;
        __bf16* dst = qT + ((size_t)(b * NH + h) * NPIX) * HD + d0;
        #pragma unroll
        for (int a = 0; a < 4; ++a) {
            const int px = px0 + 16 * a + col;
            bf16x4 v;
            #pragma unroll
            for (int r = 0; r < 4; ++r) v[r] = (__bf16)((acc[a][r] + bias4[r]) * QSCALE);
            *(bf16x4*)(dst + (size_t)px * HD) = v;
        }
    } else if (oslab < 4) {                        // ---- k ----
        const int o2 = orow - 128;
        const int h = o2 >> 5, d0 = o2 & 31;
        __bf16* dst = kT + ((size_t)(b * NH + h) * NPIX) * HD + d0;
        #pragma unroll
        for (int a = 0; a < 4; ++a) {
            const int px = px0 + 16 * a + col;
            bf16x4 v;
            #pragma unroll
            for (int r = 0; r < 4; ++r) v[r] = (__bf16)(acc[a][r] + bias4[r]);
            *(bf16x4*)(dst + (size_t)px * HD) = v;
        }
    } else {                                       // ---- v: vT + permuted vP ----
        const int c = orow - 256;
        #pragma unroll
        for (int a = 0; a < 4; ++a) {
            const int px = px0 + 16 * a + col;
            bf16x4 v;
            #pragma unroll
            for (int r = 0; r < 4; ++r) v[r] = (__bf16)(acc[a][r] + bias4[r]);
            *(bf16x4*)(vT + ((size_t)(b * NPIX + px)) * CCH + c) = v;
            const int sp = px0 + 4 * col + a;      // permuted slot of key px
            #pragma unroll
            for (int r = 0; r < 4; ++r)
                vP[((size_t)(b * CCH + c + r)) * NPIX + sp] = v[r];
        }
    }
}

// ---------------------------------------------------------------------------
// K2: flash attention + fused LePE. grid (98, 8), block 512 = 8 waves.
// Block = 32 queries; 8-way split-K (6-7 chunks of 64 keys per wave).
// Same L2 traffic as R3 but 2x waves/block for latency hiding.
// Opart overlays the P buffer after a barrier (saves 33 KB LDS -> 3 blk/CU).
// ---------------------------------------------------------------------------
__global__ __launch_bounds__(512) void k_attn(
    const __bf16* __restrict__ qT, const __bf16* __restrict__ kT,
    const __bf16* __restrict__ vP, const __bf16* __restrict__ vT,
    const float* __restrict__ lepe_w, const float* __restrict__ lepe_b,
    __bf16* __restrict__ attnT)
{
    __shared__ __bf16 P[8][32][72];        // 36.9 KB; Opart overlays after barrier
    __shared__ float  lpart[8][32];
    __shared__ float  wl[32][25];
    __shared__ float  bl[32];

    const int tid = threadIdx.x;
    const int w = tid >> 6, lane = tid & 63;
    const int col = lane & 15, g = lane >> 4;
    const int bh = blockIdx.y, b = bh >> 2, h = bh & 3;
    const int qbase = blockIdx.x * 32;
    const size_t headoff = (size_t)bh * NPIX * HD;
    const int c0h = h * HD;

    for (int i = tid; i < 800; i += 512) ((float*)wl)[i] = lepe_w[c0h * 25 + i];
    if (tid < 32) bl[tid] = lepe_b[c0h + tid];

    const bf16x8 aqA = *(const bf16x8*)(qT + headoff + (size_t)(qbase + col) * HD + g * 8);
    const bf16x8 aqB = *(const bf16x8*)(qT + headoff + (size_t)(qbase + 16 + col) * HD + g * 8);

    f32x4 O[2][2];
    #pragma unroll
    for (int i = 0; i < 2; ++i)
        #pragma unroll
        for (int j = 0; j < 2; ++j) O[i][j] = (f32x4){0.f, 0.f, 0.f, 0.f};
    float lacc[2][4] = {{0.f,0.f,0.f,0.f},{0.f,0.f,0.f,0.f}};

    const __bf16* kTh   = kT + headoff;
    const __bf16* vrow0 = vP + (size_t)(b * CCH + c0h + col)      * NPIX;
    const __bf16* vrow1 = vP + (size_t)(b * CCH + c0h + 16 + col) * NPIX;

    const int cs = (49 * w) >> 3, ce = (49 * (w + 1)) >> 3;   // 6,6,6,6,6,6,6,7

#define LOADK(DK, KK) do { const int _k0 = (KK);                                          \
        _Pragma("unroll")                                                                 \
        for (int _c = 0; _c < 4; ++_c)                                                    \
            DK[_c] = *(const bf16x8*)(kTh + (size_t)(_k0 + 16 * _c + col) * HD + g * 8);  \
        } while (0)

    auto compute = [&](const bf16x8* bk, int k0) {
        // V loads issue first; consumed only after QK+exp (~400 cyc) => latency hidden
        const bf16x8 bv0 = *(const bf16x8*)(vrow0 + k0      + g * 8);
        const bf16x8 bv1 = *(const bf16x8*)(vrow0 + k0 + 32 + g * 8);
        const bf16x8 bv2 = *(const bf16x8*)(vrow1 + k0      + g * 8);
        const bf16x8 bv3 = *(const bf16x8*)(vrow1 + k0 + 32 + g * 8);
        const f32x4 z = {0.f, 0.f, 0.f, 0.f};
        #pragma unroll
        for (int qh = 0; qh < 2; ++qh) {
            const bf16x8 aq = qh ? aqB : aqA;
            f32x4 s0 = __builtin_amdgcn_mfma_f32_16x16x32_bf16(aq, bk[0], z, 0, 0, 0);
            f32x4 s1 = __builtin_amdgcn_mfma_f32_16x16x32_bf16(aq, bk[1], z, 0, 0, 0);
            f32x4 s2 = __builtin_amdgcn_mfma_f32_16x16x32_bf16(aq, bk[2], z, 0, 0, 0);
            f32x4 s3 = __builtin_amdgcn_mfma_f32_16x16x32_bf16(aq, bk[3], z, 0, 0, 0);
            #pragma unroll
            for (int r = 0; r < 4; ++r) {
                const float p0 = FEXP2(s0[r]), p1 = FEXP2(s1[r]);
                const float p2 = FEXP2(s2[r]), p3 = FEXP2(s3[r]);
                lacc[qh][r] += (p0 + p1) + (p2 + p3);
                bf16x4 pv = {(__bf16)p0, (__bf16)p1, (__bf16)p2, (__bf16)p3};
                *(bf16x4*)&P[w][qh * 16 + g * 4 + r][4 * col] = pv;
            }
        }
        #pragma unroll
        for (int qh = 0; qh < 2; ++qh) {
            const bf16x8 ap0 = *(const bf16x8*)&P[w][qh * 16 + col][g * 8];
            const bf16x8 ap1 = *(const bf16x8*)&P[w][qh * 16 + col][32 + g * 8];
            O[qh][0] = __builtin_amdgcn_mfma_f32_16x16x32_bf16(ap0, bv0, O[qh][0], 0, 0, 0);
            O[qh][0] = __builtin_amdgcn_mfma_f32_16x16x32_bf16(ap1, bv1, O[qh][0], 0, 0, 0);
            O[qh][1] = __builtin_amdgcn_mfma_f32_16x16x32_bf16(ap0, bv2, O[qh][1], 0, 0, 0);
            O[qh][1] = __builtin_amdgcn_mfma_f32_16x16x32_bf16(ap1, bv3, O[qh][1], 0, 0, 0);
        }
    };

    bf16x8 kA[4], kB[4];
    LOADK(kA, cs * 64);
    int cc = cs;
    while (cc + 2 <= ce) {                      // K ping-pong pipeline
        LOADK(kB, (cc + 1) * 64);
        compute(kA, cc * 64);
        LOADK(kA, ((cc + 2 < ce) ? cc + 2 : cs) * 64);   // dummy reload ok
        compute(kB, (cc + 1) * 64);
        cc += 2;
    }
    if (cc < ce) compute(kA, cc * 64);          // odd tail (wave 7)
#undef LOADK

    #pragma unroll
    for (int qh = 0; qh < 2; ++qh)
        #pragma unroll
        for (int r = 0; r < 4; ++r) {
            float l = lacc[qh][r];
            l += __shfl_xor(l, 1);  l += __shfl_xor(l, 2);
            l += __shfl_xor(l, 4);  l += __shfl_xor(l, 8);
            if (col == 0) lpart[w][qh * 16 + g * 4 + r] = l;
        }

    __syncthreads();                            // all P reads done
    float (*Opart)[32][33] = (float(*)[32][33])(&P[0][0][0]);   // overlay (33.8<=36.9 KB)
    #pragma unroll
    for (int qh = 0; qh < 2; ++qh)
        #pragma unroll
        for (int r = 0; r < 4; ++r) {
            Opart[w][qh * 16 + g * 4 + r][col]      = O[qh][0][r];
            Opart[w][qh * 16 + g * 4 + r][col + 16] = O[qh][1][r];
        }
    __syncthreads();

    // epilogue over all 512 threads: (32 q) x (16 c-pairs)
    const int q  = tid >> 4;
    const int d2 = (tid & 15) * 2;
    const int px = qbase + q;
    float lt = 0.f, o0 = 0.f, o1 = 0.f;
    #pragma unroll
    for (int ww = 0; ww < 8; ++ww) {
        lt += lpart[ww][q];
        o0 += Opart[ww][q][d2];
        o1 += Opart[ww][q][d2 + 1];
    }
    const float linv = 1.0f / lt;
    o0 = o0 * linv + bl[d2];
    o1 = o1 * linv + bl[d2 + 1];

    const int py = px / WIMG, pxx = px % WIMG;
    const __bf16* vtb = vT + ((size_t)b * NPIX) * CCH + c0h + d2;
    #pragma unroll
    for (int dy = 0; dy < 5; ++dy) {
        const int yy = py + dy - 2;
        if (yy < 0 || yy >= WIMG) continue;
        #pragma unroll
        for (int dx = 0; dx < 5; ++dx) {
            const int xx = pxx + dx - 2;
            if (xx < 0 || xx >= WIMG) continue;
            const bf16x2 vv = *(const bf16x2*)(vtb + (size_t)(yy * WIMG + xx) * CCH);
            const int tap = dy * 5 + dx;
            o0 += (float)vv[0] * wl[d2][tap];
            o1 += (float)vv[1] * wl[d2 + 1][tap];
        }
    }
    bf16x2 ov = {(__bf16)o0, (__bf16)o1};
    *(bf16x2*)(attnT + ((size_t)(b * NPIX + px)) * CCH + c0h + d2) = ov;
}

// ---------------------------------------------------------------------------
// K3: out = proj_w @ (attn+lepe) + proj_b, bf16 MFMA, zero LDS.
// grid (98, 4, 2), block 256; wave tile = 16 outputs x 16 pixels.
// ---------------------------------------------------------------------------
__global__ __launch_bounds__(256) void k_proj(
    const __bf16* __restrict__ attnT, const float* __restrict__ proj_w,
    const float* __restrict__ proj_b, float* __restrict__ out)
{
    const int tid = threadIdx.x;
    const int w = tid >> 6, lane = tid & 63;
    const int col = lane & 15, g = lane >> 4;
    const int px0 = blockIdx.x * 32 + (w >> 1) * 16;
    const int obase = blockIdx.y * 32 + (w & 1) * 16;
    const int b = blockIdx.z;

    const float* wrow = proj_w + (size_t)(obase + col) * CCH;
    const __bf16* abase = attnT + (size_t)(b * NPIX + px0) * CCH;

    f32x4 acc = {0.f, 0.f, 0.f, 0.f};
    #pragma unroll
    for (int ks = 0; ks < 4; ++ks) {
        const int c0 = ks * 32 + g * 8;
        const float4 wA = *(const float4*)(wrow + c0);
        const float4 wB = *(const float4*)(wrow + c0 + 4);
        bf16x8 af = {(__bf16)wA.x, (__bf16)wA.y, (__bf16)wA.z, (__bf16)wA.w,
                     (__bf16)wB.x, (__bf16)wB.y, (__bf16)wB.z, (__bf16)wB.w};
        const bf16x8 bf_ = *(const bf16x8*)(abase + (size_t)col * CCH + c0);
        acc = __builtin_amdgcn_mfma_f32_16x16x32_bf16(af, bf_, acc, 0, 0, 0);
    }

    const f32x4 pb = *(const f32x4*)(proj_b + obase + g * 4);
    #pragma unroll
    for (int r = 0; r < 4; ++r)
        out[(size_t)(b * CCH + obase + g * 4 + r) * NPIX + px0 + col] = acc[r] + pb[r];
}

// ---------------------------------------------------------------------------
extern "C" void kernel_launch(void* const* d_in, const int* in_sizes, int n_in,
                              void* d_out, int out_size, void* d_ws, size_t ws_size,
                              hipStream_t stream)
{
    const float* x      = (const float*)d_in[0];
    const float* qkv_w  = (const float*)d_in[1];
    const float* qkv_b  = (const float*)d_in[2];
    const float* lepe_w = (const float*)d_in[3];
    const float* lepe_b = (const float*)d_in[4];
    const float* proj_w = (const float*)d_in[5];
    const float* proj_b = (const float*)d_in[6];
    float* out = (float*)d_out;

    char* p = (char*)d_ws;                                   // 8.03 MB total
    __bf16* qT = (__bf16*)p;    p += (size_t)2 * NH * NPIX * HD * 2;
    __bf16* kT = (__bf16*)p;    p += (size_t)2 * NH * NPIX * HD * 2;
    __bf16* vT = (__bf16*)p;    p += (size_t)2 * NPIX * CCH * 2;
    __bf16* vP = (__bf16*)p;    p += (size_t)2 * CCH * NPIX * 2;
    __bf16* attnT = (__bf16*)p;

    k_qkv <<<dim3(49, 6, 2), dim3(256), 0, stream>>>(x, qkv_w, qkv_b, qT, kT, vT, vP);
    k_attn<<<dim3(98, 8),    dim3(512), 0, stream>>>(qT, kT, vP, vT, lepe_w, lepe_b, attnT);
    k_proj<<<dim3(98, 4, 2), dim3(256), 0, stream>>>(attnT, proj_w, proj_b, out);
}

// Round 5
// 136.149 us; speedup vs baseline: 1.0978x; 1.0978x over previous
//
#include <hip/hip_runtime.h>

typedef __bf16 bf16x8 __attribute__((ext_vector_type(8)));
typedef __bf16 bf16x4 __attribute__((ext_vector_type(4)));
typedef __bf16 bf16x2 __attribute__((ext_vector_type(2)));
typedef float  f32x4  __attribute__((ext_vector_type(4)));

#define NPIX  3136      // 56*56 = 49*64 = 98*32 (no tails)
#define WIMG  56
#define CCH   128
#define NH    4
#define HD    32
#define NSPLIT 8        // key-splits per (head, 32q) tile
// 32^-0.5 * log2(e): q pre-scaled so softmax uses exp2 directly
#define QSCALE 0.2550565470841439f

#if __has_builtin(__builtin_amdgcn_exp2f)
#define FEXP2(x) __builtin_amdgcn_exp2f(x)
#else
#define FEXP2(x) __expf((x) * 0.6931471805599453f)
#endif

// MFMA 16x16x32 fragment maps (HW-verified R1-R4):
//   A[m=lane&15][k=(lane>>4)*8+j]   B[k=(lane>>4)*8+j][n=lane&15]
//   D: col(n)=lane&15, row(m)=(lane>>4)*4+reg
// Key permutation inside each 64-key block: storage s holds key 16*(s&3)+(s>>2)
// so QK chunk-c output packs to slot 4*col+c (one b64 LDS write/lane); vP is
// pre-permuted to match (summation-index permutation = free).

// ---------------------------------------------------------------------------
// K1: qkv = qkv_w @ x + qkv_b, bf16 MFMA (M=384, K=128, N=6272).  (R4 kernel)
// ---------------------------------------------------------------------------
__global__ __launch_bounds__(256) void k_qkv(
    const float* __restrict__ x, const float* __restrict__ qkv_w,
    const float* __restrict__ qkv_b,
    __bf16* __restrict__ qT, __bf16* __restrict__ kT,
    __bf16* __restrict__ vT, __bf16* __restrict__ vP)
{
    __shared__ __bf16 xl[64][136];                 // [px][c], row stride 272B
    const int tid = threadIdx.x;
    const int w = tid >> 6, lane = tid & 63;
    const int col = lane & 15, g = lane >> 4;
    const int px0 = blockIdx.x * 64;
    const int oslab = blockIdx.y;                  // 0-1 q, 2-3 k, 4-5 v
    const int b = blockIdx.z;
    const int obase = oslab * 64 + w * 16;

    {   // stage: wave w handles 4-channel groups; coalesced dword loads
        const int px = tid & 63, cq = tid >> 6;
        const float* xp = x + (size_t)b * CCH * NPIX + px0 + px;
        #pragma unroll
        for (int i = 0; i < 8; ++i) {
            const int c0 = cq * 4 + i * 16;
            const float v0 = xp[(size_t)(c0 + 0) * NPIX];
            const float v1 = xp[(size_t)(c0 + 1) * NPIX];
            const float v2 = xp[(size_t)(c0 + 2) * NPIX];
            const float v3 = xp[(size_t)(c0 + 3) * NPIX];
            bf16x4 bv = {(__bf16)v0, (__bf16)v1, (__bf16)v2, (__bf16)v3};
            *(bf16x4*)&xl[px][c0] = bv;
        }
    }
    __syncthreads();

    f32x4 acc[4];
    #pragma unroll
    for (int a = 0; a < 4; ++a) acc[a] = (f32x4){0.f, 0.f, 0.f, 0.f};

    const float* wrow = qkv_w + (size_t)(obase + col) * CCH;
    #pragma unroll
    for (int ks = 0; ks < 4; ++ks) {
        const int c0 = ks * 32 + g * 8;
        const float4 wA = *(const float4*)(wrow + c0);
        const float4 wB = *(const float4*)(wrow + c0 + 4);
        bf16x8 af = {(__bf16)wA.x, (__bf16)wA.y, (__bf16)wA.z, (__bf16)wA.w,
                     (__bf16)wB.x, (__bf16)wB.y, (__bf16)wB.z, (__bf16)wB.w};
        #pragma unroll
        for (int a = 0; a < 4; ++a) {
            const bf16x8 bf_ = *(const bf16x8*)&xl[16 * a + col][c0];  // one b128
            acc[a] = __builtin_amdgcn_mfma_f32_16x16x32_bf16(af, bf_, acc[a], 0, 0, 0);
        }
    }

    const int orow = obase + g * 4;
    const f32x4 bias4 = *(const f32x4*)(qkv_b + orow);

    if (oslab < 2) {                               // ---- q (scaled) ----
        const int h = orow >> 5, d0 = orow & 31;
        __bf16* dst = qT + ((size_t)(b * NH + h) * NPIX) * HD + d0;
        #pragma unroll
        for (int a = 0; a < 4; ++a) {
            const int px = px0 + 16 * a + col;
            bf16x4 v;
            #pragma unroll
            for (int r = 0; r < 4; ++r) v[r] = (__bf16)((acc[a][r] + bias4[r]) * QSCALE);
            *(bf16x4*)(dst + (size_t)px * HD) = v;
        }
    } else if (oslab < 4) {                        // ---- k ----
        const int o2 = orow - 128;
        const int h = o2 >> 5, d0 = o2 & 31;
        __bf16* dst = kT + ((size_t)(b * NH + h) * NPIX) * HD + d0;
        #pragma unroll
        for (int a = 0; a < 4; ++a) {
            const int px = px0 + 16 * a + col;
            bf16x4 v;
            #pragma unroll
            for (int r = 0; r < 4; ++r) v[r] = (__bf16)(acc[a][r] + bias4[r]);
            *(bf16x4*)(dst + (size_t)px * HD) = v;
        }
    } else {                                       // ---- v: vT + permuted vP ----
        const int c = orow - 256;
        #pragma unroll
        for (int a = 0; a < 4; ++a) {
            const int px = px0 + 16 * a + col;
            bf16x4 v;
            #pragma unroll
            for (int r = 0; r < 4; ++r) v[r] = (__bf16)(acc[a][r] + bias4[r]);
            *(bf16x4*)(vT + ((size_t)(b * NPIX + px)) * CCH + c) = v;
            const int sp = px0 + 4 * col + a;      // permuted slot of key px
            #pragma unroll
            for (int r = 0; r < 4; ++r)
                vP[((size_t)(b * CCH + c + r)) * NPIX + sp] = v[r];
        }
    }
}

// ---------------------------------------------------------------------------
// K2: attention partials. ONE WAVE per workgroup (64 thr, 4.6 KB LDS) --
// residency is grid-limited (~24 waves/CU), no barriers, no cross-wave work.
// grid (98 qtiles, 8 heads, 8 splits). Wave: 32 queries x 6-7 key-chunks.
// Row-sum l computed by MFMA vs all-ones B (kills per-chunk VALU adds).
// Outputs UNNORMALIZED: pO bf16 [t][s][d 32][q 32], pl f32 [t][s][q 32].
// ---------------------------------------------------------------------------
__global__ __launch_bounds__(64, 4) void k_attn(
    const __bf16* __restrict__ qT, const __bf16* __restrict__ kT,
    const __bf16* __restrict__ vP,
    __bf16* __restrict__ pO, float* __restrict__ pl)
{
    __shared__ __bf16 P[32][72];           // wave-private P tile
    const int lane = threadIdx.x;
    const int col = lane & 15, g = lane >> 4;
    const int qt = blockIdx.x, bh = blockIdx.y, sp = blockIdx.z;
    const int b = bh >> 2, h = bh & 3;
    const int qbase = qt * 32;
    const size_t headoff = (size_t)bh * NPIX * HD;
    const int c0h = h * HD;

    const bf16x8 aqA = *(const bf16x8*)(qT + headoff + (size_t)(qbase + col) * HD + g * 8);
    const bf16x8 aqB = *(const bf16x8*)(qT + headoff + (size_t)(qbase + 16 + col) * HD + g * 8);

    const __bf16 one = (__bf16)1.0f;
    const bf16x8 ones = {one, one, one, one, one, one, one, one};

    f32x4 O[2][2], Lacc[2];
    #pragma unroll
    for (int i = 0; i < 2; ++i) {
        Lacc[i] = (f32x4){0.f, 0.f, 0.f, 0.f};
        #pragma unroll
        for (int j = 0; j < 2; ++j) O[i][j] = (f32x4){0.f, 0.f, 0.f, 0.f};
    }

    const __bf16* kTh   = kT + headoff;
    const __bf16* vrow0 = vP + (size_t)(b * CCH + c0h + col)      * NPIX;
    const __bf16* vrow1 = vP + (size_t)(b * CCH + c0h + 16 + col) * NPIX;

    const int cs = (49 * sp) >> 3, ce = (49 * (sp + 1)) >> 3;   // 6 or 7 chunks

#define LOADK(DK, KK) do { const int _k0 = (KK);                                          \
        _Pragma("unroll")                                                                 \
        for (int _c = 0; _c < 4; ++_c)                                                    \
            DK[_c] = *(const bf16x8*)(kTh + (size_t)(_k0 + 16 * _c + col) * HD + g * 8);  \
        } while (0)

    auto compute = [&](const bf16x8* bk, int k0) {
        const bf16x8 bv0 = *(const bf16x8*)(vrow0 + k0      + g * 8);
        const bf16x8 bv1 = *(const bf16x8*)(vrow0 + k0 + 32 + g * 8);
        const bf16x8 bv2 = *(const bf16x8*)(vrow1 + k0      + g * 8);
        const bf16x8 bv3 = *(const bf16x8*)(vrow1 + k0 + 32 + g * 8);
        const f32x4 z = {0.f, 0.f, 0.f, 0.f};
        #pragma unroll
        for (int qh = 0; qh < 2; ++qh) {
            const bf16x8 aq = qh ? aqB : aqA;
            f32x4 s0 = __builtin_amdgcn_mfma_f32_16x16x32_bf16(aq, bk[0], z, 0, 0, 0);
            f32x4 s1 = __builtin_amdgcn_mfma_f32_16x16x32_bf16(aq, bk[1], z, 0, 0, 0);
            f32x4 s2 = __builtin_amdgcn_mfma_f32_16x16x32_bf16(aq, bk[2], z, 0, 0, 0);
            f32x4 s3 = __builtin_amdgcn_mfma_f32_16x16x32_bf16(aq, bk[3], z, 0, 0, 0);
            #pragma unroll
            for (int r = 0; r < 4; ++r) {
                bf16x4 pv = {(__bf16)FEXP2(s0[r]), (__bf16)FEXP2(s1[r]),
                             (__bf16)FEXP2(s2[r]), (__bf16)FEXP2(s3[r])};
                *(bf16x4*)&P[qh * 16 + g * 4 + r][4 * col] = pv;   // one b64
            }
        }
        #pragma unroll
        for (int qh = 0; qh < 2; ++qh) {
            const bf16x8 ap0 = *(const bf16x8*)&P[qh * 16 + col][g * 8];
            const bf16x8 ap1 = *(const bf16x8*)&P[qh * 16 + col][32 + g * 8];
            O[qh][0] = __builtin_amdgcn_mfma_f32_16x16x32_bf16(ap0, bv0, O[qh][0], 0, 0, 0);
            O[qh][0] = __builtin_amdgcn_mfma_f32_16x16x32_bf16(ap1, bv1, O[qh][0], 0, 0, 0);
            O[qh][1] = __builtin_amdgcn_mfma_f32_16x16x32_bf16(ap0, bv2, O[qh][1], 0, 0, 0);
            O[qh][1] = __builtin_amdgcn_mfma_f32_16x16x32_bf16(ap1, bv3, O[qh][1], 0, 0, 0);
            Lacc[qh] = __builtin_amdgcn_mfma_f32_16x16x32_bf16(ap0, ones, Lacc[qh], 0, 0, 0);
            Lacc[qh] = __builtin_amdgcn_mfma_f32_16x16x32_bf16(ap1, ones, Lacc[qh], 0, 0, 0);
        }
    };

    bf16x8 kA[4], kB[4];
    LOADK(kA, cs * 64);
    int cc = cs;
    while (cc + 2 <= ce) {                      // K ping-pong pipeline
        LOADK(kB, (cc + 1) * 64);
        compute(kA, cc * 64);
        LOADK(kA, ((cc + 2 < ce) ? cc + 2 : cs) * 64);   // dummy reload ok
        compute(kB, (cc + 1) * 64);
        cc += 2;
    }
    if (cc < ce) compute(kA, cc * 64);          // odd tail (7-chunk splits)
#undef LOADK

    // store partials: pO[t][s][d][q] bf16 (q contiguous per lane), pl f32
    const int t = bh * 98 + qt;
    __bf16* po = pO + ((size_t)t * NSPLIT + sp) * 1024;
    #pragma unroll
    for (int qh = 0; qh < 2; ++qh)
        #pragma unroll
        for (int dh = 0; dh < 2; ++dh) {
            bf16x4 v = {(__bf16)O[qh][dh][0], (__bf16)O[qh][dh][1],
                        (__bf16)O[qh][dh][2], (__bf16)O[qh][dh][3]};
            *(bf16x4*)(po + (dh * 16 + col) * 32 + qh * 16 + g * 4) = v;
        }
    if (col == 0) {
        float* plp = pl + ((size_t)t * NSPLIT + sp) * 32;
        *(f32x4*)(plp + g * 4)      = Lacc[0];
        *(f32x4*)(plp + 16 + g * 4) = Lacc[1];
    }
}

// ---------------------------------------------------------------------------
// K2b: reduce 8 split partials, normalize, + LePE + bias, write attnT [px][c].
// grid (98, 8), block 256: thread = (q, 4-channel group).
// ---------------------------------------------------------------------------
__global__ __launch_bounds__(256) void k_reduce(
    const __bf16* __restrict__ pO, const float* __restrict__ pl,
    const __bf16* __restrict__ vT,
    const float* __restrict__ lepe_w, const float* __restrict__ lepe_b,
    __bf16* __restrict__ attnT)
{
    __shared__ float wl[32][25];
    __shared__ float bl[32];
    const int tid = threadIdx.x;
    const int qt = blockIdx.x, bh = blockIdx.y;
    const int b = bh >> 2, h = bh & 3;
    const int c0h = h * HD;

    for (int i = tid; i < 800; i += 256) ((float*)wl)[i] = lepe_w[c0h * 25 + i];
    if (tid < 32) bl[tid] = lepe_b[c0h + tid];
    __syncthreads();

    const int q = tid >> 3;                    // 0..31
    const int cq = (tid & 7) * 4;              // 0,4,...,28
    const int t = bh * 98 + qt;

    float lt = 0.f;
    float o[4] = {0.f, 0.f, 0.f, 0.f};
    #pragma unroll
    for (int s = 0; s < NSPLIT; ++s) {
        lt += pl[((size_t)t * NSPLIT + s) * 32 + q];
        const __bf16* base = pO + ((size_t)t * NSPLIT + s) * 1024 + q;
        #pragma unroll
        for (int i = 0; i < 4; ++i) o[i] += (float)base[(cq + i) * 32];
    }
    const float linv = 1.0f / lt;
    #pragma unroll
    for (int i = 0; i < 4; ++i) o[i] = o[i] * linv + bl[cq + i];

    const int px = qt * 32 + q;
    const int py = px / WIMG, pxx = px % WIMG;
    const __bf16* vtb = vT + ((size_t)b * NPIX) * CCH + c0h + cq;
    #pragma unroll
    for (int dy = 0; dy < 5; ++dy) {
        const int yy = py + dy - 2;
        if (yy < 0 || yy >= WIMG) continue;
        #pragma unroll
        for (int dx = 0; dx < 5; ++dx) {
            const int xx = pxx + dx - 2;
            if (xx < 0 || xx >= WIMG) continue;
            const bf16x4 vv = *(const bf16x4*)(vtb + (size_t)(yy * WIMG + xx) * CCH);
            const int tap = dy * 5 + dx;
            #pragma unroll
            for (int i = 0; i < 4; ++i) o[i] += (float)vv[i] * wl[cq + i][tap];
        }
    }
    bf16x4 ov = {(__bf16)o[0], (__bf16)o[1], (__bf16)o[2], (__bf16)o[3]};
    *(bf16x4*)(attnT + ((size_t)(b * NPIX + px)) * CCH + c0h + cq) = ov;
}

// ---------------------------------------------------------------------------
// K3: out = proj_w @ (attn+lepe) + proj_b, bf16 MFMA, zero LDS.  (R4 kernel)
// ---------------------------------------------------------------------------
__global__ __launch_bounds__(256) void k_proj(
    const __bf16* __restrict__ attnT, const float* __restrict__ proj_w,
    const float* __restrict__ proj_b, float* __restrict__ out)
{
    const int tid = threadIdx.x;
    const int w = tid >> 6, lane = tid & 63;
    const int col = lane & 15, g = lane >> 4;
    const int px0 = blockIdx.x * 32 + (w >> 1) * 16;
    const int obase = blockIdx.y * 32 + (w & 1) * 16;
    const int b = blockIdx.z;

    const float* wrow = proj_w + (size_t)(obase + col) * CCH;
    const __bf16* abase = attnT + (size_t)(b * NPIX + px0) * CCH;

    f32x4 acc = {0.f, 0.f, 0.f, 0.f};
    #pragma unroll
    for (int ks = 0; ks < 4; ++ks) {
        const int c0 = ks * 32 + g * 8;
        const float4 wA = *(const float4*)(wrow + c0);
        const float4 wB = *(const float4*)(wrow + c0 + 4);
        bf16x8 af = {(__bf16)wA.x, (__bf16)wA.y, (__bf16)wA.z, (__bf16)wA.w,
                     (__bf16)wB.x, (__bf16)wB.y, (__bf16)wB.z, (__bf16)wB.w};
        const bf16x8 bf_ = *(const bf16x8*)(abase + (size_t)col * CCH + c0);
        acc = __builtin_amdgcn_mfma_f32_16x16x32_bf16(af, bf_, acc, 0, 0, 0);
    }

    const f32x4 pb = *(const f32x4*)(proj_b + obase + g * 4);
    #pragma unroll
    for (int r = 0; r < 4; ++r)
        out[(size_t)(b * CCH + obase + g * 4 + r) * NPIX + px0 + col] = acc[r] + pb[r];
}

// ---------------------------------------------------------------------------
extern "C" void kernel_launch(void* const* d_in, const int* in_sizes, int n_in,
                              void* d_out, int out_size, void* d_ws, size_t ws_size,
                              hipStream_t stream)
{
    const float* x      = (const float*)d_in[0];
    const float* qkv_w  = (const float*)d_in[1];
    const float* qkv_b  = (const float*)d_in[2];
    const float* lepe_w = (const float*)d_in[3];
    const float* lepe_b = (const float*)d_in[4];
    const float* proj_w = (const float*)d_in[5];
    const float* proj_b = (const float*)d_in[6];
    float* out = (float*)d_out;

    char* p = (char*)d_ws;                                   // ~21.7 MB total
    __bf16* qT    = (__bf16*)p;  p += (size_t)2 * NH * NPIX * HD * 2;   // 1.6 MB
    __bf16* kT    = (__bf16*)p;  p += (size_t)2 * NH * NPIX * HD * 2;   // 1.6 MB
    __bf16* vT    = (__bf16*)p;  p += (size_t)2 * NPIX * CCH * 2;       // 1.6 MB
    __bf16* vP    = (__bf16*)p;  p += (size_t)2 * CCH * NPIX * 2;       // 1.6 MB
    __bf16* attnT = (__bf16*)p;  p += (size_t)2 * NPIX * CCH * 2;       // 1.6 MB
    __bf16* pO    = (__bf16*)p;  p += (size_t)784 * NSPLIT * 1024 * 2;  // 12.8 MB
    float*  pl    = (float*)p;                                          // 0.8 MB

    k_qkv   <<<dim3(49, 6, 2), dim3(256), 0, stream>>>(x, qkv_w, qkv_b, qT, kT, vT, vP);
    k_attn  <<<dim3(98, 8, NSPLIT), dim3(64), 0, stream>>>(qT, kT, vP, pO, pl);
    k_reduce<<<dim3(98, 8),    dim3(256), 0, stream>>>(pO, pl, vT, lepe_w, lepe_b, attnT);
    k_proj  <<<dim3(98, 4, 2), dim3(256), 0, stream>>>(attnT, proj_w, proj_b, out);
}